// Round 2
// baseline (600.445 us; speedup 1.0000x reference)
//
#include <hip/hip_runtime.h>
#include <hip/hip_bf16.h>
#include <stdint.h>

// Problem constants
#define DM 768     // d_model
#define DK 64      // d_k per head
#define NH 12      // heads
#define SQ 4096    // sequence length
#define BB 2       // batch

typedef __attribute__((ext_vector_type(8))) short bf16x8;
typedef __attribute__((ext_vector_type(4))) float f32x4;
typedef __attribute__((ext_vector_type(4))) unsigned short u16x4;
typedef unsigned short u16;
typedef unsigned int   u32;

__device__ __forceinline__ float bf2f(u16 x) {
    u32 t = ((u32)x) << 16;
    return __builtin_bit_cast(float, t);
}
__device__ __forceinline__ u16 f2bf(float f) {
    u32 u = __builtin_bit_cast(u32, f);
    u32 r = (u + 0x7fffu + ((u >> 16) & 1u)) >> 16;   // round-nearest-even
    return (u16)r;
}

// ---------------------------------------------------------------------------
// GEMM: C[m,n] = sum_k A[m,k] * W[n,k] + bias[n]
// W:[768,768] f32 row-major, bias f32. A is f32 (AF32=1) or bf16 (AF32=0).
// Internally bf16 MFMA, f32 accum. OUTF32 ? f32 out : bf16 out.
// 128x128 tile, BK=32, 4 waves (2x2), 4x4 16x16x32 frags per wave.
// ---------------------------------------------------------------------------
#define BM 128
#define BN 128
#define BKK 32
#define LDT 40   // padded LDS row stride (elements)

template<bool AF32, bool OUTF32>
__global__ __launch_bounds__(256) void gemm_bt_bias(
    const void* __restrict__ Av, const float* __restrict__ W,
    const float* __restrict__ bias, void* __restrict__ Cv)
{
    __shared__ u16 Asm[BM * LDT];
    __shared__ u16 Bsm[BM * LDT];

    const int tid  = threadIdx.x;
    const int lane = tid & 63;
    const int w    = tid >> 6;
    const int wr   = w >> 1, wc = w & 1;
    const int l16  = lane & 15, lg = lane >> 4;

    const int ntiles = DM / BN;                 // 6
    const int mt = blockIdx.x / ntiles;
    const int nt = blockIdx.x % ntiles;
    const int m0 = mt * BM, n0 = nt * BN;

    f32x4 acc[4][4];
    for (int mi = 0; mi < 4; ++mi)
        for (int ni = 0; ni < 4; ++ni)
            for (int r = 0; r < 4; ++r) acc[mi][ni][r] = 0.f;

    for (int k0 = 0; k0 < DM; k0 += BKK) {
        // stage W-tile [128][32]: f32 -> bf16 (4 float4 per thread)
        for (int i = 0; i < 4; ++i) {
            int c   = tid + i * 256;            // 0..1023
            int row = c >> 3;                   // 0..127
            int cv  = c & 7;                    // float4 slot
            float4 b4 = *(const float4*)&W[(size_t)(n0 + row) * DM + k0 + cv * 4];
            u16x4 bb; bb.x = f2bf(b4.x); bb.y = f2bf(b4.y);
            bb.z = f2bf(b4.z); bb.w = f2bf(b4.w);
            *(u16x4*)&Bsm[row * LDT + cv * 4] = bb;
        }
        // stage A-tile [128][32]
        if (AF32) {
            const float* A = (const float*)Av;
            for (int i = 0; i < 4; ++i) {
                int c   = tid + i * 256;
                int row = c >> 3;
                int cv  = c & 7;
                float4 a4 = *(const float4*)&A[(size_t)(m0 + row) * DM + k0 + cv * 4];
                u16x4 ab; ab.x = f2bf(a4.x); ab.y = f2bf(a4.y);
                ab.z = f2bf(a4.z); ab.w = f2bf(a4.w);
                *(u16x4*)&Asm[row * LDT + cv * 4] = ab;
            }
        } else {
            const u16* A = (const u16*)Av;
            for (int i = 0; i < 2; ++i) {
                int c   = tid + i * 256;        // 0..511
                int row = c >> 2;               // 0..127
                int col = (c & 3) * 8;          // bf16x8 slot
                *(uint4*)&Asm[row * LDT + col] =
                    *(const uint4*)&A[(size_t)(m0 + row) * DM + k0 + col];
            }
        }
        __syncthreads();

        bf16x8 af[4], bfr[4];
        for (int mi = 0; mi < 4; ++mi)
            af[mi]  = *(const bf16x8*)&Asm[(wr * 64 + mi * 16 + l16) * LDT + lg * 8];
        for (int ni = 0; ni < 4; ++ni)
            bfr[ni] = *(const bf16x8*)&Bsm[(wc * 64 + ni * 16 + l16) * LDT + lg * 8];

        for (int mi = 0; mi < 4; ++mi)
            for (int ni = 0; ni < 4; ++ni)
                acc[mi][ni] = __builtin_amdgcn_mfma_f32_16x16x32_bf16(
                    af[mi], bfr[ni], acc[mi][ni], 0, 0, 0);
        __syncthreads();
    }

    // epilogue: bias + store
    for (int mi = 0; mi < 4; ++mi)
        for (int ni = 0; ni < 4; ++ni) {
            int n = n0 + wc * 64 + ni * 16 + l16;
            float bv = bias[n];
            for (int r = 0; r < 4; ++r) {
                int m = m0 + wr * 64 + mi * 16 + lg * 4 + r;
                float v = acc[mi][ni][r] + bv;
                if (OUTF32) ((float*)Cv)[(size_t)m * DM + n] = v;
                else        ((u16*)Cv)[(size_t)m * DM + n]   = f2bf(v);
            }
        }
}

// ---------------------------------------------------------------------------
// Flash attention fwd over bf16 intermediates in ws.
// Layouts: q/k/v/o all [B, S, H*DK]. Block: 256 thr = 4 waves; each wave owns
// 16 q rows (QBLK=64); KV tile = 64.
// ---------------------------------------------------------------------------
#define QBLK 64
#define KBLK 64
#define KLD 72
#define PLD 72

__global__ __launch_bounds__(256) void flash_attn(
    const u16* __restrict__ Qm, const u16* __restrict__ Km,
    const u16* __restrict__ Vm, u16* __restrict__ Om)
{
    __shared__ u16 Ksm[KBLK * KLD];     // [kv=64][d=64] row-major
    __shared__ u16 Vsm[DK * KLD];       // transposed: [d=64][kv=64]
    __shared__ u16 Psm[4][16 * PLD];    // per-wave P tile [16 q][64 kv]

    const int tid  = threadIdx.x;
    const int lane = tid & 63;
    const int w    = tid >> 6;
    const int l16  = lane & 15, lg = lane >> 4;

    const int qt = blockIdx.x;          // 0..63
    const int bh = blockIdx.y;          // 0..23
    const int b  = bh / NH, h = bh % NH;
    const size_t base = (size_t)b * SQ * DM + (size_t)h * DK;

    const int q0 = qt * QBLK + w * 16;

    // Q fragments, pre-scaled by 1/sqrt(64)=0.125 (exact in bf16)
    bf16x8 qf[2];
    for (int ks = 0; ks < 2; ++ks) {
        bf16x8 v = *(const bf16x8*)&Qm[base + (size_t)(q0 + l16) * DM + ks * 32 + lg * 8];
        bf16x8 o;
        for (int i = 0; i < 8; ++i) o[i] = (short)f2bf(bf2f((u16)v[i]) * 0.125f);
        qf[ks] = o;
    }

    f32x4 accO[4];
    for (int d = 0; d < 4; ++d)
        for (int r = 0; r < 4; ++r) accO[d][r] = 0.f;
    float mrun[4], lrun[4];
    for (int r = 0; r < 4; ++r) { mrun[r] = -1e30f; lrun[r] = 0.f; }

    for (int kv0 = 0; kv0 < SQ; kv0 += KBLK) {
        // stage K row-major, V transposed
        for (int i = 0; i < 2; ++i) {
            int c   = tid + i * 256;
            int row = c >> 3;
            int col = (c & 7) * 8;
            *(uint4*)&Ksm[row * KLD + col] =
                *(const uint4*)&Km[base + (size_t)(kv0 + row) * DM + col];
            bf16x8 vv = *(const bf16x8*)&Vm[base + (size_t)(kv0 + row) * DM + col];
            for (int j = 0; j < 8; ++j)
                Vsm[(col + j) * KLD + row] = (u16)vv[j];
        }
        __syncthreads();

        // S = Q K^T (scaled)
        f32x4 sc[4];
        for (int g = 0; g < 4; ++g) {
            f32x4 a;
            for (int r = 0; r < 4; ++r) a[r] = 0.f;
            for (int ks = 0; ks < 2; ++ks) {
                bf16x8 kf = *(const bf16x8*)&Ksm[(g * 16 + l16) * KLD + ks * 32 + lg * 8];
                a = __builtin_amdgcn_mfma_f32_16x16x32_bf16(qf[ks], kf, a, 0, 0, 0);
            }
            sc[g] = a;
        }

        // online softmax; q-row (lg*4+r), kv col = g*16+l16; reduce across l16
        float alpha[4];
        for (int r = 0; r < 4; ++r) {
            float mx = fmaxf(fmaxf(sc[0][r], sc[1][r]), fmaxf(sc[2][r], sc[3][r]));
            mx = fmaxf(mx, __shfl_xor(mx, 1));
            mx = fmaxf(mx, __shfl_xor(mx, 2));
            mx = fmaxf(mx, __shfl_xor(mx, 4));
            mx = fmaxf(mx, __shfl_xor(mx, 8));
            float mnew = fmaxf(mrun[r], mx);
            float al   = __expf(mrun[r] - mnew);
            float rs   = 0.f;
            for (int g = 0; g < 4; ++g) {
                float p = __expf(sc[g][r] - mnew);
                sc[g][r] = p;
                rs += p;
            }
            rs += __shfl_xor(rs, 1);
            rs += __shfl_xor(rs, 2);
            rs += __shfl_xor(rs, 4);
            rs += __shfl_xor(rs, 8);
            lrun[r]  = lrun[r] * al + rs;
            mrun[r]  = mnew;
            alpha[r] = al;
        }
        for (int d = 0; d < 4; ++d)
            for (int r = 0; r < 4; ++r) accO[d][r] *= alpha[r];

        // P -> LDS, wave-private
        u16* Pw = &Psm[w][0];
        for (int g = 0; g < 4; ++g)
            for (int r = 0; r < 4; ++r)
                Pw[(lg * 4 + r) * PLD + g * 16 + l16] = f2bf(sc[g][r]);

        // O += P V
        bf16x8 pa[2];
        for (int ks = 0; ks < 2; ++ks)
            pa[ks] = *(const bf16x8*)&Pw[l16 * PLD + ks * 32 + lg * 8];
        for (int d = 0; d < 4; ++d)
            for (int ks = 0; ks < 2; ++ks) {
                bf16x8 vf = *(const bf16x8*)&Vsm[(d * 16 + l16) * KLD + ks * 32 + lg * 8];
                accO[d] = __builtin_amdgcn_mfma_f32_16x16x32_bf16(pa[ks], vf, accO[d], 0, 0, 0);
            }
        __syncthreads();
    }

    // normalize + store
    for (int d = 0; d < 4; ++d)
        for (int r = 0; r < 4; ++r) {
            float v = accO[d][r] / lrun[r];
            Om[base + (size_t)(q0 + lg * 4 + r) * DM + d * 16 + l16] = f2bf(v);
        }
}

// ---------------------------------------------------------------------------
extern "C" void kernel_launch(void* const* d_in, const int* in_sizes, int n_in,
                              void* d_out, int out_size, void* d_ws, size_t ws_size,
                              hipStream_t stream)
{
    const float* Q  = (const float*)d_in[0];
    const float* K  = (const float*)d_in[1];
    const float* V  = (const float*)d_in[2];
    const float* Wq = (const float*)d_in[3];
    const float* bq = (const float*)d_in[4];
    const float* Wk = (const float*)d_in[5];
    const float* bk = (const float*)d_in[6];
    const float* Wv = (const float*)d_in[7];
    const float* bv = (const float*)d_in[8];
    const float* Wo = (const float*)d_in[9];
    const float* bo = (const float*)d_in[10];
    (void)in_sizes; (void)n_in; (void)out_size; (void)ws_size;

    const size_t elems = (size_t)BB * SQ * DM;   // 6291456 per tensor
    u16* qws = (u16*)d_ws;
    u16* kws = qws + elems;
    u16* vws = kws + elems;
    u16* aws = vws + elems;

    dim3 gg((BB * SQ / BM) * (DM / BN));         // 64*6 = 384
    dim3 bt(256);

    hipLaunchKernelGGL((gemm_bt_bias<true, false>),  gg, bt, 0, stream, (const void*)Q, Wq, bq, (void*)qws);
    hipLaunchKernelGGL((gemm_bt_bias<true, false>),  gg, bt, 0, stream, (const void*)K, Wk, bk, (void*)kws);
    hipLaunchKernelGGL((gemm_bt_bias<true, false>),  gg, bt, 0, stream, (const void*)V, Wv, bv, (void*)vws);

    dim3 ga(SQ / QBLK, BB * NH);                 // (64, 24)
    hipLaunchKernelGGL(flash_attn, ga, bt, 0, stream, qws, kws, vws, aws);

    hipLaunchKernelGGL((gemm_bt_bias<false, true>), gg, bt, 0, stream, (const void*)aws, Wo, bo, d_out);
}

// Round 3
// 304.878 us; speedup vs baseline: 1.9695x; 1.9695x over previous
//
#include <hip/hip_runtime.h>
#include <hip/hip_bf16.h>
#include <stdint.h>

#define DM 768
#define DK 64
#define NH 12
#define SQ 4096
#define BB 2

typedef __attribute__((ext_vector_type(8))) short bf16x8;
typedef __attribute__((ext_vector_type(4))) float f32x4;
typedef __attribute__((ext_vector_type(16))) float f32x16;
typedef __attribute__((ext_vector_type(4))) unsigned short u16x4;
typedef __attribute__((ext_vector_type(4))) unsigned int u32x4;
typedef unsigned short u16;
typedef unsigned int   u32;

__device__ __forceinline__ float bf2f(u16 x) {
    u32 t = ((u32)x) << 16;
    return __builtin_bit_cast(float, t);
}
__device__ __forceinline__ u16 f2bf(float f) {
    u32 u = __builtin_bit_cast(u32, f);
    u32 r = (u + 0x7fffu + ((u >> 16) & 1u)) >> 16;   // RNE
    return (u16)r;
}

// ---------------------------------------------------------------------------
// GEMM: C[m,n] = (sum_k A[m,k] * W[n,k] + bias[n]) * oscale
// MODE_A: 0 = f32 A, 1 = bf16 A.  MODE_OUT: 0 = bf16 row-major, 1 = f32
// row-major, 2 = bf16 V^T layout VT[((b*NH+h)*DK+d)*SQ+kv].
// 128x128 tile, BK=32, 4 waves (2x2), 4x4 16x16x32 frags.
// ---------------------------------------------------------------------------
#define BM 128
#define BN 128
#define BKK 32
#define LDT 40

template<int MODE_A, int MODE_OUT>
__global__ __launch_bounds__(256) void gemm_bt_bias(
    const void* __restrict__ Av, const float* __restrict__ W,
    const float* __restrict__ bias, void* __restrict__ Cv, float oscale)
{
    __shared__ u16 Asm[BM * LDT];
    __shared__ u16 Bsm[BM * LDT];

    const int tid  = threadIdx.x;
    const int lane = tid & 63;
    const int w    = tid >> 6;
    const int wr   = w >> 1, wc = w & 1;
    const int l16  = lane & 15, lg = lane >> 4;

    const int ntiles = DM / BN;                 // 6
    const int mt = blockIdx.x / ntiles;
    const int nt = blockIdx.x % ntiles;
    const int m0 = mt * BM, n0 = nt * BN;

    f32x4 acc[4][4];
    #pragma unroll
    for (int mi = 0; mi < 4; ++mi)
        #pragma unroll
        for (int ni = 0; ni < 4; ++ni)
            #pragma unroll
            for (int r = 0; r < 4; ++r) acc[mi][ni][r] = 0.f;

    for (int k0 = 0; k0 < DM; k0 += BKK) {
        #pragma unroll
        for (int i = 0; i < 4; ++i) {
            int c   = tid + i * 256;
            int row = c >> 3;
            int cv  = c & 7;
            float4 b4 = *(const float4*)&W[(size_t)(n0 + row) * DM + k0 + cv * 4];
            u16x4 bb; bb.x = f2bf(b4.x); bb.y = f2bf(b4.y);
            bb.z = f2bf(b4.z); bb.w = f2bf(b4.w);
            *(u16x4*)&Bsm[row * LDT + cv * 4] = bb;
        }
        if (MODE_A == 0) {
            const float* A = (const float*)Av;
            #pragma unroll
            for (int i = 0; i < 4; ++i) {
                int c   = tid + i * 256;
                int row = c >> 3;
                int cv  = c & 7;
                float4 a4 = *(const float4*)&A[(size_t)(m0 + row) * DM + k0 + cv * 4];
                u16x4 ab; ab.x = f2bf(a4.x); ab.y = f2bf(a4.y);
                ab.z = f2bf(a4.z); ab.w = f2bf(a4.w);
                *(u16x4*)&Asm[row * LDT + cv * 4] = ab;
            }
        } else {
            const u16* A = (const u16*)Av;
            #pragma unroll
            for (int i = 0; i < 2; ++i) {
                int c   = tid + i * 256;
                int row = c >> 2;
                int col = (c & 3) * 8;
                *(uint4*)&Asm[row * LDT + col] =
                    *(const uint4*)&A[(size_t)(m0 + row) * DM + k0 + col];
            }
        }
        __syncthreads();

        bf16x8 af[4], bfr[4];
        #pragma unroll
        for (int mi = 0; mi < 4; ++mi)
            af[mi]  = *(const bf16x8*)&Asm[(wr * 64 + mi * 16 + l16) * LDT + lg * 8];
        #pragma unroll
        for (int ni = 0; ni < 4; ++ni)
            bfr[ni] = *(const bf16x8*)&Bsm[(wc * 64 + ni * 16 + l16) * LDT + lg * 8];

        #pragma unroll
        for (int mi = 0; mi < 4; ++mi)
            #pragma unroll
            for (int ni = 0; ni < 4; ++ni)
                acc[mi][ni] = __builtin_amdgcn_mfma_f32_16x16x32_bf16(
                    af[mi], bfr[ni], acc[mi][ni], 0, 0, 0);
        __syncthreads();
    }

    #pragma unroll
    for (int mi = 0; mi < 4; ++mi)
        #pragma unroll
        for (int ni = 0; ni < 4; ++ni) {
            int n = n0 + wc * 64 + ni * 16 + l16;
            float bv = bias[n];
            if (MODE_OUT == 2) {
                // V^T: n -> (h,d); m -> (b,kv); 4 consecutive kv per lane
                int hh = n >> 6, dd = n & 63;
                int mb = m0 + wr * 64 + mi * 16 + lg * 4;
                int bI = mb >> 12;
                int kv = mb & (SQ - 1);
                u16x4 pk;
                #pragma unroll
                for (int r = 0; r < 4; ++r)
                    pk[r] = f2bf((acc[mi][ni][r] + bv) * oscale);
                *(u16x4*)&((u16*)Cv)[(((size_t)bI * NH + hh) * DK + dd) * SQ + kv] = pk;
            } else {
                #pragma unroll
                for (int r = 0; r < 4; ++r) {
                    int m = m0 + wr * 64 + mi * 16 + lg * 4 + r;
                    float v = (acc[mi][ni][r] + bv) * oscale;
                    if (MODE_OUT == 1) ((float*)Cv)[(size_t)m * DM + n] = v;
                    else               ((u16*)Cv)[(size_t)m * DM + n]   = f2bf(v);
                }
            }
        }
}

// ---------------------------------------------------------------------------
// Flash attention, swapped-operand 32x32 structure.
// Q (bf16, pre-scaled by 0.125), K row-major [B,S,768]; V^T as VT[bh][d][kv].
// Block = 4 waves; wave owns 32 q rows; KV tile = 64.
// S^T = mfma(K_frag, Q_frag): lane owns q = lane&31, kv split by hi = lane>>5.
// O^T accumulated as mfma(V^T_frag, P^T_frag): col=q per lane.
// LDS: K and V^T tiles, 64x64 each, 128B rows, XOR-swizzled (col16 ^= row&7).
// ---------------------------------------------------------------------------
__global__ __launch_bounds__(256, 2) void flash_attn32(
    const u16* __restrict__ Qm, const u16* __restrict__ Km,
    const u16* __restrict__ VT, u16* __restrict__ Om)
{
    __shared__ __align__(16) u16 Ksm[64 * 64];
    __shared__ __align__(16) u16 Vsm[64 * 64];

    const int tid  = threadIdx.x;
    const int lane = tid & 63;
    const int w    = tid >> 6;
    const int kvL  = lane & 31;
    const int hi   = lane >> 5;

    const int qt = blockIdx.x;          // 0..31
    const int bh = blockIdx.y;          // 0..23
    const int b  = bh / NH, h = bh % NH;
    const size_t baseQ  = (size_t)b * SQ * DM + (size_t)h * DK;
    const size_t baseVT = (size_t)bh * DK * SQ;

    const int q = qt * 128 + w * 32 + kvL;

    // Q fragments (already scaled): qf[j] holds Q[q][16j + 8*hi .. +8]
    bf16x8 qf[4];
    #pragma unroll
    for (int j = 0; j < 4; ++j)
        qf[j] = *(const bf16x8*)&Qm[baseQ + (size_t)q * DM + j * 16 + hi * 8];

    f32x16 accO[2];
    #pragma unroll
    for (int e = 0; e < 16; ++e) { accO[0][e] = 0.f; accO[1][e] = 0.f; }
    float mrun = -1e30f, lrun = 0.f;

    const int srow = tid >> 2;          // 0..63
    const int sc   = tid & 3;
    const int swzr = srow & 7;

    for (int kv0 = 0; kv0 < SQ; kv0 += 64) {
        // stage K rows (kv) and V^T rows (d), both 64x128B, swizzled
        #pragma unroll
        for (int i = 0; i < 2; ++i) {
            int c = sc + i * 4;         // 0..7
            uint4 kd = *(const uint4*)&Km[baseQ + (size_t)(kv0 + srow) * DM + c * 8];
            uint4 vd = *(const uint4*)&VT[baseVT + (size_t)srow * SQ + kv0 + c * 8];
            int dst = srow * 128 + ((c ^ swzr) << 4);
            *(uint4*)((char*)Ksm + dst) = kd;
            *(uint4*)((char*)Vsm + dst) = vd;
        }
        __syncthreads();

        // S^T = K . Q  (two 32-kv halves)
        f32x16 s0, s1;
        #pragma unroll
        for (int e = 0; e < 16; ++e) { s0[e] = 0.f; s1[e] = 0.f; }
        #pragma unroll
        for (int j = 0; j < 4; ++j) {
            int col = ((2 * j + hi) ^ (kvL & 7)) << 4;
            bf16x8 kf0 = *(const bf16x8*)((char*)Ksm + kvL * 128 + col);
            bf16x8 kf1 = *(const bf16x8*)((char*)Ksm + (32 + kvL) * 128 + col);
            s0 = __builtin_amdgcn_mfma_f32_32x32x16_bf16(kf0, qf[j], s0, 0, 0, 0);
            s1 = __builtin_amdgcn_mfma_f32_32x32x16_bf16(kf1, qf[j], s1, 0, 0, 0);
        }

        // online softmax — lane owns one q row; halves exchanged via shfl_xor 32
        float mx = s0[0];
        #pragma unroll
        for (int e = 1; e < 16; ++e) mx = fmaxf(mx, s0[e]);
        #pragma unroll
        for (int e = 0; e < 16; ++e) mx = fmaxf(mx, s1[e]);
        mx = fmaxf(mx, __shfl_xor(mx, 32));
        float mnew = fmaxf(mrun, mx);
        float al = __expf(mrun - mnew);
        float p0[16], p1[16];
        float rs = 0.f;
        #pragma unroll
        for (int e = 0; e < 16; ++e) { p0[e] = __expf(s0[e] - mnew); rs += p0[e]; }
        #pragma unroll
        for (int e = 0; e < 16; ++e) { p1[e] = __expf(s1[e] - mnew); rs += p1[e]; }
        rs += __shfl_xor(rs, 32);
        lrun = lrun * al + rs;
        mrun = mnew;
        #pragma unroll
        for (int e = 0; e < 16; ++e) { accO[0][e] *= al; accO[1][e] *= al; }

        // pack P to bf16 words; kv pair of word wd (s half): 2*(wd&1)+8*(wd>>1)+4*hi+32*s
        u32 pb[16], sw[16];
        #pragma unroll
        for (int wd = 0; wd < 8; ++wd) {
            pb[wd]     = (u32)f2bf(p0[2 * wd]) | ((u32)f2bf(p0[2 * wd + 1]) << 16);
            pb[8 + wd] = (u32)f2bf(p1[2 * wd]) | ((u32)f2bf(p1[2 * wd + 1]) << 16);
        }
        #pragma unroll
        for (int wd = 0; wd < 16; ++wd) sw[wd] = (u32)__shfl_xor((int)pb[wd], 32);

        // B-fragments for PV, one per 16-kv chunk m
        bf16x8 Bp[4];
        #pragma unroll
        for (int m = 0; m < 4; ++m) {
            int sb = (m >> 1) * 8 + (m & 1) * 4;
            u32x4 wds;
            wds[0] = hi ? sw[sb + 2] : pb[sb + 0];
            wds[1] = hi ? sw[sb + 3] : pb[sb + 1];
            wds[2] = hi ? pb[sb + 2] : sw[sb + 0];
            wds[3] = hi ? pb[sb + 3] : sw[sb + 1];
            Bp[m] = __builtin_bit_cast(bf16x8, wds);
        }

        // O^T += V^T . P^T
        #pragma unroll
        for (int m = 0; m < 4; ++m) {
            int col = ((2 * m + hi) ^ (kvL & 7)) << 4;
            bf16x8 v0 = *(const bf16x8*)((char*)Vsm + kvL * 128 + col);
            bf16x8 v1 = *(const bf16x8*)((char*)Vsm + (32 + kvL) * 128 + col);
            accO[0] = __builtin_amdgcn_mfma_f32_32x32x16_bf16(v0, Bp[m], accO[0], 0, 0, 0);
            accO[1] = __builtin_amdgcn_mfma_f32_32x32x16_bf16(v1, Bp[m], accO[1], 0, 0, 0);
        }
        __syncthreads();
    }

    // normalize + store: acc reg g -> d = (g&3) + 8*(g>>2) + 4*hi + 32*c
    float inv = 1.f / lrun;
    #pragma unroll
    for (int c = 0; c < 2; ++c)
        #pragma unroll
        for (int t = 0; t < 4; ++t) {
            int d0 = t * 8 + hi * 4 + c * 32;
            u16x4 pk;
            #pragma unroll
            for (int u = 0; u < 4; ++u) pk[u] = f2bf(accO[c][t * 4 + u] * inv);
            *(u16x4*)&Om[baseQ + (size_t)q * DM + d0] = pk;
        }
}

// ---------------------------------------------------------------------------
extern "C" void kernel_launch(void* const* d_in, const int* in_sizes, int n_in,
                              void* d_out, int out_size, void* d_ws, size_t ws_size,
                              hipStream_t stream)
{
    const float* Q  = (const float*)d_in[0];
    const float* K  = (const float*)d_in[1];
    const float* V  = (const float*)d_in[2];
    const float* Wq = (const float*)d_in[3];
    const float* bq = (const float*)d_in[4];
    const float* Wk = (const float*)d_in[5];
    const float* bk = (const float*)d_in[6];
    const float* Wv = (const float*)d_in[7];
    const float* bv = (const float*)d_in[8];
    const float* Wo = (const float*)d_in[9];
    const float* bo = (const float*)d_in[10];
    (void)in_sizes; (void)n_in; (void)out_size; (void)ws_size;

    const size_t elems = (size_t)BB * SQ * DM;
    u16* qws  = (u16*)d_ws;
    u16* kws  = qws + elems;
    u16* vtws = kws + elems;
    u16* aws  = vtws + elems;

    dim3 gg((BB * SQ / BM) * (DM / BN));         // 384
    dim3 bt(256);

    hipLaunchKernelGGL((gemm_bt_bias<0, 0>), gg, bt, 0, stream,
                       (const void*)Q, Wq, bq, (void*)qws, 0.125f);
    hipLaunchKernelGGL((gemm_bt_bias<0, 0>), gg, bt, 0, stream,
                       (const void*)K, Wk, bk, (void*)kws, 1.0f);
    hipLaunchKernelGGL((gemm_bt_bias<0, 2>), gg, bt, 0, stream,
                       (const void*)V, Wv, bv, (void*)vtws, 1.0f);

    dim3 ga(SQ / 128, BB * NH);                  // (32, 24)
    hipLaunchKernelGGL(flash_attn32, ga, bt, 0, stream, qws, kws, vtws, aws);

    hipLaunchKernelGGL((gemm_bt_bias<1, 1>), gg, bt, 0, stream,
                       (const void*)aws, Wo, bo, d_out, 1.0f);
}

// Round 6
// 278.237 us; speedup vs baseline: 2.1580x; 1.0957x over previous
//
#include <hip/hip_runtime.h>
#include <hip/hip_bf16.h>
#include <stdint.h>

#define DM 768
#define DK 64
#define NH 12
#define SQ 4096
#define BB 2

typedef __attribute__((ext_vector_type(8))) short bf16x8;
typedef __attribute__((ext_vector_type(4))) float f32x4;
typedef __attribute__((ext_vector_type(16))) float f32x16;
typedef __attribute__((ext_vector_type(4))) unsigned short u16x4;
typedef __attribute__((ext_vector_type(4))) unsigned int u32x4;
typedef unsigned short u16;
typedef unsigned int   u32;

__device__ __forceinline__ float bf2f(u16 x) {
    u32 t = ((u32)x) << 16;
    return __builtin_bit_cast(float, t);
}
__device__ __forceinline__ u16 f2bf(float f) {
    u32 u = __builtin_bit_cast(u32, f);
    u32 r = (u + 0x7fffu + ((u >> 16) & 1u)) >> 16;   // RNE
    return (u16)r;
}
// pack two positive f32 -> (bf16,bf16) via byte-select truncation.
// v_perm_b32 semantics (documented): dst.byte[i] = sel.byte[i] < 4 ?
// S1.byte[sel] : S0.byte[sel-4].  sel 0x07060302 -> {hi.b3,hi.b2,lo.b3,lo.b2}
// = (trunc_bf16(hi)<<16) | trunc_bf16(lo).
__device__ __forceinline__ u32 pack_trunc(float lo, float hi) {
    return __builtin_amdgcn_perm(__builtin_bit_cast(u32, hi),
                                 __builtin_bit_cast(u32, lo), 0x07060302u);
}

// ---------------------------------------------------------------------------
// GEMM: C[m,n] = (sum_k A[m,k] * W[n,k] + bias[n]) * oscale
// MODE_A: 0 = f32 A, 1 = bf16 A.  MODE_OUT: 0 = bf16 row-major, 1 = f32
// row-major, 2 = bf16 V^T layout VT[((b*NH+h)*DK+d)*SQ+kv].
// ---------------------------------------------------------------------------
#define BM 128
#define BN 128
#define BKK 32
#define LDT 40

template<int MODE_A, int MODE_OUT>
__global__ __launch_bounds__(256) void gemm_bt_bias(
    const void* __restrict__ Av, const float* __restrict__ W,
    const float* __restrict__ bias, void* __restrict__ Cv, float oscale)
{
    __shared__ u16 Asm[BM * LDT];
    __shared__ u16 Bsm[BM * LDT];

    const int tid  = threadIdx.x;
    const int lane = tid & 63;
    const int w    = tid >> 6;
    const int wr   = w >> 1, wc = w & 1;
    const int l16  = lane & 15, lg = lane >> 4;

    const int ntiles = DM / BN;                 // 6
    const int mt = blockIdx.x / ntiles;
    const int nt = blockIdx.x % ntiles;
    const int m0 = mt * BM, n0 = nt * BN;

    f32x4 acc[4][4];
    #pragma unroll
    for (int mi = 0; mi < 4; ++mi)
        #pragma unroll
        for (int ni = 0; ni < 4; ++ni)
            #pragma unroll
            for (int r = 0; r < 4; ++r) acc[mi][ni][r] = 0.f;

    for (int k0 = 0; k0 < DM; k0 += BKK) {
        #pragma unroll
        for (int i = 0; i < 4; ++i) {
            int c   = tid + i * 256;
            int row = c >> 3;
            int cv  = c & 7;
            float4 b4 = *(const float4*)&W[(size_t)(n0 + row) * DM + k0 + cv * 4];
            u16x4 bb; bb.x = f2bf(b4.x); bb.y = f2bf(b4.y);
            bb.z = f2bf(b4.z); bb.w = f2bf(b4.w);
            *(u16x4*)&Bsm[row * LDT + cv * 4] = bb;
        }
        if (MODE_A == 0) {
            const float* A = (const float*)Av;
            #pragma unroll
            for (int i = 0; i < 4; ++i) {
                int c   = tid + i * 256;
                int row = c >> 3;
                int cv  = c & 7;
                float4 a4 = *(const float4*)&A[(size_t)(m0 + row) * DM + k0 + cv * 4];
                u16x4 ab; ab.x = f2bf(a4.x); ab.y = f2bf(a4.y);
                ab.z = f2bf(a4.z); ab.w = f2bf(a4.w);
                *(u16x4*)&Asm[row * LDT + cv * 4] = ab;
            }
        } else {
            const u16* A = (const u16*)Av;
            #pragma unroll
            for (int i = 0; i < 2; ++i) {
                int c   = tid + i * 256;
                int row = c >> 2;
                int col = (c & 3) * 8;
                *(uint4*)&Asm[row * LDT + col] =
                    *(const uint4*)&A[(size_t)(m0 + row) * DM + k0 + col];
            }
        }
        __syncthreads();

        bf16x8 af[4], bfr[4];
        #pragma unroll
        for (int mi = 0; mi < 4; ++mi)
            af[mi]  = *(const bf16x8*)&Asm[(wr * 64 + mi * 16 + l16) * LDT + lg * 8];
        #pragma unroll
        for (int ni = 0; ni < 4; ++ni)
            bfr[ni] = *(const bf16x8*)&Bsm[(wc * 64 + ni * 16 + l16) * LDT + lg * 8];

        #pragma unroll
        for (int mi = 0; mi < 4; ++mi)
            #pragma unroll
            for (int ni = 0; ni < 4; ++ni)
                acc[mi][ni] = __builtin_amdgcn_mfma_f32_16x16x32_bf16(
                    af[mi], bfr[ni], acc[mi][ni], 0, 0, 0);
        __syncthreads();
    }

    #pragma unroll
    for (int mi = 0; mi < 4; ++mi)
        #pragma unroll
        for (int ni = 0; ni < 4; ++ni) {
            int n = n0 + wc * 64 + ni * 16 + l16;
            float bv = bias[n];
            if (MODE_OUT == 2) {
                int hh = n >> 6, dd = n & 63;
                int mb = m0 + wr * 64 + mi * 16 + lg * 4;
                int bI = mb >> 12;
                int kv = mb & (SQ - 1);
                u16x4 pk;
                #pragma unroll
                for (int r = 0; r < 4; ++r)
                    pk[r] = f2bf((acc[mi][ni][r] + bv) * oscale);
                *(u16x4*)&((u16*)Cv)[(((size_t)bI * NH + hh) * DK + dd) * SQ + kv] = pk;
            } else {
                #pragma unroll
                for (int r = 0; r < 4; ++r) {
                    int m = m0 + wr * 64 + mi * 16 + lg * 4 + r;
                    float v = (acc[mi][ni][r] + bv) * oscale;
                    if (MODE_OUT == 1) ((float*)Cv)[(size_t)m * DM + n] = v;
                    else               ((u16*)Cv)[(size_t)m * DM + n]   = f2bf(v);
                }
            }
        }
}

// ---------------------------------------------------------------------------
// Flash attention, swapped-operand 32x32, log2-domain softmax.
// Q pre-scaled by 0.125*log2(e); p = 2^(s - m) via v_exp_f32.
// All cross-lane ops via __shfl_xor (HW-verified in round 3); P pack via
// documented v_perm_b32 truncation. No inline asm.
// ---------------------------------------------------------------------------
__global__ __launch_bounds__(256, 2) void flash_attn32(
    const u16* __restrict__ Qm, const u16* __restrict__ Km,
    const u16* __restrict__ VT, u16* __restrict__ Om)
{
    __shared__ __align__(16) u16 Ksm[64 * 64];
    __shared__ __align__(16) u16 Vsm[64 * 64];

    const int tid  = threadIdx.x;
    const int lane = tid & 63;
    const int w    = tid >> 6;
    const int kvL  = lane & 31;
    const int hi   = lane >> 5;

    const int qt = blockIdx.x;          // 0..31
    const int bh = blockIdx.y;          // 0..23
    const int b  = bh / NH, h = bh % NH;
    const size_t baseQ  = (size_t)b * SQ * DM + (size_t)h * DK;
    const size_t baseVT = (size_t)bh * DK * SQ;

    const int q = qt * 128 + w * 32 + kvL;

    bf16x8 qf[4];
    #pragma unroll
    for (int j = 0; j < 4; ++j)
        qf[j] = *(const bf16x8*)&Qm[baseQ + (size_t)q * DM + j * 16 + hi * 8];

    // loop-invariant swizzled LDS byte offsets (slot (2j+hi) of row kvL)
    int off[4];
    #pragma unroll
    for (int j = 0; j < 4; ++j)
        off[j] = kvL * 128 + (((2 * j + hi) ^ (kvL & 7)) << 4);

    f32x16 accO[2];
    #pragma unroll
    for (int e = 0; e < 16; ++e) { accO[0][e] = 0.f; accO[1][e] = 0.f; }
    float mrun = -1e30f, lrun = 0.f;

    const int srow = tid >> 2;          // 0..63
    const int sc   = tid & 3;
    const int swzr = srow & 7;

    for (int kv0 = 0; kv0 < SQ; kv0 += 64) {
        #pragma unroll
        for (int i = 0; i < 2; ++i) {
            int c = sc + i * 4;
            uint4 kd = *(const uint4*)&Km[baseQ + (size_t)(kv0 + srow) * DM + c * 8];
            uint4 vd = *(const uint4*)&VT[baseVT + (size_t)srow * SQ + kv0 + c * 8];
            int dst = srow * 128 + ((c ^ swzr) << 4);
            *(uint4*)((char*)Ksm + dst) = kd;
            *(uint4*)((char*)Vsm + dst) = vd;
        }
        __syncthreads();

        // S^T = K . Q (log2 domain)
        f32x16 s0, s1;
        #pragma unroll
        for (int e = 0; e < 16; ++e) { s0[e] = 0.f; s1[e] = 0.f; }
        __builtin_amdgcn_s_setprio(1);
        #pragma unroll
        for (int j = 0; j < 4; ++j) {
            bf16x8 kf0 = *(const bf16x8*)((char*)Ksm + off[j]);
            bf16x8 kf1 = *(const bf16x8*)((char*)Ksm + 4096 + off[j]);
            s0 = __builtin_amdgcn_mfma_f32_32x32x16_bf16(kf0, qf[j], s0, 0, 0, 0);
            s1 = __builtin_amdgcn_mfma_f32_32x32x16_bf16(kf1, qf[j], s1, 0, 0, 0);
        }
        __builtin_amdgcn_s_setprio(0);

        // row max (v_max3-fusable triples) + cross-half via shfl
        float mx = fmaxf(s0[0], s0[1]);
        #pragma unroll
        for (int e = 2; e < 16; e += 2) mx = fmaxf(fmaxf(mx, s0[e]), s0[e + 1]);
        #pragma unroll
        for (int e = 0; e < 16; e += 2) mx = fmaxf(fmaxf(mx, s1[e]), s1[e + 1]);
        mx = fmaxf(mx, __shfl_xor(mx, 32));

        // defer-max: rescale only when max grows past threshold (log2 units)
        if (__any(mx > mrun + 8.f)) {
            float mnew = fmaxf(mrun, mx);
            float al = __builtin_amdgcn_exp2f(mrun - mnew);
            lrun *= al;
            #pragma unroll
            for (int e = 0; e < 16; ++e) { accO[0][e] *= al; accO[1][e] *= al; }
            mrun = mnew;
        }

        // p = 2^(s-m), pack to bf16 pairs (truncation), accumulate row sum
        u32 pb[16];
        float rs0 = 0.f, rs1 = 0.f;
        #pragma unroll
        for (int wd = 0; wd < 8; ++wd) {
            float a0 = __builtin_amdgcn_exp2f(s0[2 * wd]     - mrun);
            float a1 = __builtin_amdgcn_exp2f(s0[2 * wd + 1] - mrun);
            float b0 = __builtin_amdgcn_exp2f(s1[2 * wd]     - mrun);
            float b1 = __builtin_amdgcn_exp2f(s1[2 * wd + 1] - mrun);
            rs0 += a0 + a1;
            rs1 += b0 + b1;
            pb[wd]     = pack_trunc(a0, a1);
            pb[8 + wd] = pack_trunc(b0, b1);
        }
        {
            float rs = rs0 + rs1;
            rs += __shfl_xor(rs, 32);
            lrun += rs;
        }

        // redistribute P words across lane halves (HW-verified round-3 pattern)
        u32 sw[16];
        #pragma unroll
        for (int wd = 0; wd < 16; ++wd) sw[wd] = (u32)__shfl_xor((int)pb[wd], 32);

        // O^T += V^T . P^T
        __builtin_amdgcn_s_setprio(1);
        #pragma unroll
        for (int m = 0; m < 4; ++m) {
            int sb = 4 * m;
            u32x4 wds;
            wds[0] = hi ? sw[sb + 2] : pb[sb + 0];
            wds[1] = hi ? sw[sb + 3] : pb[sb + 1];
            wds[2] = hi ? pb[sb + 2] : sw[sb + 0];
            wds[3] = hi ? pb[sb + 3] : sw[sb + 1];
            bf16x8 Bp = __builtin_bit_cast(bf16x8, wds);
            bf16x8 v0 = *(const bf16x8*)((char*)Vsm + off[m]);
            bf16x8 v1 = *(const bf16x8*)((char*)Vsm + 4096 + off[m]);
            accO[0] = __builtin_amdgcn_mfma_f32_32x32x16_bf16(v0, Bp, accO[0], 0, 0, 0);
            accO[1] = __builtin_amdgcn_mfma_f32_32x32x16_bf16(v1, Bp, accO[1], 0, 0, 0);
        }
        __builtin_amdgcn_s_setprio(0);
        __syncthreads();
    }

    float inv = 1.f / lrun;
    #pragma unroll
    for (int c = 0; c < 2; ++c)
        #pragma unroll
        for (int t = 0; t < 4; ++t) {
            int d0 = t * 8 + hi * 4 + c * 32;
            u16x4 pk;
            #pragma unroll
            for (int u = 0; u < 4; ++u) pk[u] = f2bf(accO[c][t * 4 + u] * inv);
            *(u16x4*)&Om[baseQ + (size_t)q * DM + d0] = pk;
        }
}

// ---------------------------------------------------------------------------
extern "C" void kernel_launch(void* const* d_in, const int* in_sizes, int n_in,
                              void* d_out, int out_size, void* d_ws, size_t ws_size,
                              hipStream_t stream)
{
    const float* Q  = (const float*)d_in[0];
    const float* K  = (const float*)d_in[1];
    const float* V  = (const float*)d_in[2];
    const float* Wq = (const float*)d_in[3];
    const float* bq = (const float*)d_in[4];
    const float* Wk = (const float*)d_in[5];
    const float* bk = (const float*)d_in[6];
    const float* Wv = (const float*)d_in[7];
    const float* bv = (const float*)d_in[8];
    const float* Wo = (const float*)d_in[9];
    const float* bo = (const float*)d_in[10];
    (void)in_sizes; (void)n_in; (void)out_size; (void)ws_size;

    const size_t elems = (size_t)BB * SQ * DM;
    u16* qws  = (u16*)d_ws;
    u16* kws  = qws + elems;
    u16* vtws = kws + elems;
    u16* aws  = vtws + elems;

    dim3 gg((BB * SQ / BM) * (DM / BN));         // 384
    dim3 bt(256);

    const float qscale = 0.125f * 1.4426950408889634f;   // 1/sqrt(64) * log2(e)

    hipLaunchKernelGGL((gemm_bt_bias<0, 0>), gg, bt, 0, stream,
                       (const void*)Q, Wq, bq, (void*)qws, qscale);
    hipLaunchKernelGGL((gemm_bt_bias<0, 0>), gg, bt, 0, stream,
                       (const void*)K, Wk, bk, (void*)kws, 1.0f);
    hipLaunchKernelGGL((gemm_bt_bias<0, 2>), gg, bt, 0, stream,
                       (const void*)V, Wv, bv, (void*)vtws, 1.0f);

    dim3 ga(SQ / 128, BB * NH);                  // (32, 24)
    hipLaunchKernelGGL(flash_attn32, ga, bt, 0, stream, qws, kws, vtws, aws);

    hipLaunchKernelGGL((gemm_bt_bias<1, 1>), gg, bt, 0, stream,
                       (const void*)aws, Wo, bo, d_out, 1.0f);
}